// Round 9
// baseline (235.367 us; speedup 1.0000x reference)
//
#include <hip/hip_runtime.h>
#include <stdint.h>

#define FEAT 128
#define NNODES 512
#define BATCH 4
#define EDGES 97920              // sum_{r=257}^{511} r ; 32 | EDGES
#define BE (BATCH*EDGES)         // 391680
#define NSAMP 5
#define BASE_OFF 32896           // 256*257/2
#define CHUNKS 40                // gumbel blocks per (b,s)
#define NWT (BE/32)              // 12240 wave-tiles (32 edges per wave)
#define MLP_GRID 510             // 510 x 4 waves x 6 tiles = 12240 exactly
#define MAP_BLOCKS 383           // ceil(EDGES/256)

typedef float f32x4 __attribute__((ext_vector_type(4)));
typedef short s16x8 __attribute__((ext_vector_type(8)));

// ---------------- threefry2x32 (exact JAX core, key=[0,42]) ------------------
__device__ __forceinline__ void threefry2x32(uint32_t k0, uint32_t k1,
                                             uint32_t& x0, uint32_t& x1) {
  uint32_t k2 = k0 ^ k1 ^ 0x1BD11BDAu;
  x0 += k0; x1 += k1;
#define RR(r) { x0 += x1; x1 = (x1 << (r)) | (x1 >> (32 - (r))); x1 ^= x0; }
  RR(13) RR(15) RR(26) RR(6)   x0 += k1; x1 += k2 + 1u;
  RR(17) RR(29) RR(16) RR(24)  x0 += k2; x1 += k0 + 2u;
  RR(13) RR(15) RR(26) RR(6)   x0 += k0; x1 += k1 + 3u;
  RR(17) RR(29) RR(16) RR(24)  x0 += k1; x1 += k2 + 4u;
  RR(13) RR(15) RR(26) RR(6)   x0 += k2; x1 += k0 + 5u;
#undef RR
}

// partitionable threefry gumbel, fp32 logs (verified passing rounds 7-8)
__device__ __forceinline__ float gumbel_valf(uint32_t n) {
  uint32_t x0 = 0u, x1 = n;
  threefry2x32(0u, 42u, x0, x1);
  uint32_t bits = x0 ^ x1;
  uint32_t fb = (bits >> 9) | 0x3f800000u;
  float f = __uint_as_float(fb) - 1.0f;
  float u = fmaxf(f, 1.1754943508222875e-38f);
  return -logf(-logf(u));
}

// ---------------- fused setup: pq (blk<256) | map (256..638) | prep (639) ----
__global__ __launch_bounds__(256) void setup_kernel(
    const float* __restrict__ nodes, const float* __restrict__ W1,
    const float* __restrict__ b1, const float* __restrict__ W2,
    const float* __restrict__ g1, const float* __restrict__ be1,
    const float* __restrict__ b2, const float* __restrict__ g2,
    const float* __restrict__ be2, const float* __restrict__ W3,
    const float* __restrict__ b3, float* __restrict__ P, float* __restrict__ Q,
    int2* __restrict__ map, unsigned short* __restrict__ GFH,
    unsigned short* __restrict__ GFL, float* __restrict__ SB,
    float* __restrict__ GW3, float* __restrict__ SC) {
  const int blk = blockIdx.x;
  const int tid = threadIdx.x;
  if (blk < 256) {
    // ---- pq: P = nodes @ W1_top + b1, Q = nodes @ W1_bot, row-major ----
    __shared__ float snode[8][FEAT];
    const int row0 = blk * 8;
    for (int i = tid; i < 8 * FEAT; i += 256)
      snode[i >> 7][i & 127] = nodes[row0 * FEAT + i];
    __syncthreads();
    const int j = tid & 127;
    const int half = tid >> 7;
    const float* w = W1 + half * FEAT * FEAT + j;
    float acc[8] = {0, 0, 0, 0, 0, 0, 0, 0};
    for (int k = 0; k < FEAT; ++k) {
      float wv = w[k * FEAT];
#pragma unroll
      for (int m = 0; m < 8; ++m) acc[m] += snode[m][k] * wv;
    }
    const float bv = half ? 0.0f : b1[j];
    float* out = half ? Q : P;
#pragma unroll
    for (int m = 0; m < 8; ++m) out[(row0 + m) * FEAT + j] = acc[m] + bv;
  } else if (blk < 256 + MAP_BLOCKS) {
    // ---- map: edge -> (sink, src) ----
    int e = (blk - 256) * 256 + tid;
    if (e < EDGES) {
      double x = (double)(e + BASE_OFF);
      int s = (int)((1.0 + sqrt(1.0 + 8.0 * x)) * 0.5);
      while ((long long)s * (s - 1) / 2 - BASE_OFF > e) --s;
      while ((long long)(s + 1) * s / 2 - BASE_OFF <= e) ++s;
      int src = e - (int)((long long)s * (s - 1) / 2 - BASE_OFF);
      map[e] = make_int2(s, src);
    }
  } else {
    // ---- prep: B-fragments of G = g1*W2 in bf16 hi/lo + SB/GW3/SC ----
    // GF*[(kt*8+nt)*64+lane][j] = bf16(G[k][n]), n=nt*16+(lane&15),
    // k=kt*32+(lane>>4)*8+j   (verified round 8)
    for (int idx = tid; idx < FEAT * FEAT; idx += 256) {
      const int j = idx & 7;
      const int lane = (idx >> 3) & 63;
      const int nt = (idx >> 9) & 7;
      const int kt = (idx >> 12) & 3;
      const int n = nt * 16 + (lane & 15);
      const int k = kt * 32 + ((lane >> 4) << 3) + j;
      const float g = g1[k] * W2[k * FEAT + n];
      const uint32_t gu = __float_as_uint(g);
      const float d = g - __uint_as_float(gu & 0xFFFF0000u);
      GFH[idx] = (unsigned short)(gu >> 16);
      GFL[idx] = (unsigned short)(__float_as_uint(d) >> 16);
    }
    if (tid < FEAT) {
      float sb = 0.f;
      for (int k = 0; k < FEAT; ++k)
        sb = fmaf(be1[k], W2[k * FEAT + tid], sb);
      SB[tid] = sb + b2[tid];
      GW3[tid] = g2[tid] * W3[tid];
    }
    __syncthreads();
    if (tid == 0) {
      float a = 0.f, c = 0.f;
      for (int n = 0; n < FEAT; ++n) { a += GW3[n]; c = fmaf(be2[n], W3[n], c); }
      SC[0] = a; SC[1] = c + b3[0];
    }
  }
}

// ---------------- main MLP kernel (MFMA) --------------------------------------
// B fragments staged ONCE per block into 64 KB LDS (2 blocks/CU).
// A loaded direct from global in fragment layout: lane (cl,qd) owns edges
// m = cl, 16+cl and k-slice qd*8..qd*8+7 per kt. LN1 stats via 2 shuffles over
// the qd-group; normalize + bf16 hi/lo split fused into A-frag build.
// 3-product bf16-split MFMA (verified round 8). No spills: ~164 VGPR + acc.
__global__ __launch_bounds__(256, 2) void mlp_kernel(
    const float* __restrict__ P, const float* __restrict__ Q,
    const int2* __restrict__ map,
    const unsigned short* __restrict__ GFH,
    const unsigned short* __restrict__ GFL,
    const float* __restrict__ SB, const float* __restrict__ GW3,
    const float* __restrict__ SC, float* __restrict__ logits) {
  __shared__ s16x8 sBH[2048];                // 32 KB
  __shared__ s16x8 sBL[2048];                // 32 KB
  const int tid = threadIdx.x;
  const int lane = tid & 63;
  const int wave = tid >> 6;
  const int cl = lane & 15;                   // C/D col, A row (m) lane
  const int qd = lane >> 4;                   // quad: A k-group, C/D row group

  {
    const float4* s1 = (const float4*)GFH;
    const float4* s2 = (const float4*)GFL;
    float4* d1 = (float4*)sBH;
    float4* d2 = (float4*)sBL;
    for (int i = tid; i < 2048; i += 256) { d1[i] = s1[i]; d2[i] = s2[i]; }
  }
  __syncthreads();

  float SBv[8], GWv[8];
#pragma unroll
  for (int nt = 0; nt < 8; ++nt) {
    SBv[nt] = SB[nt * 16 + cl];
    GWv[nt] = GW3[nt * 16 + cl];
  }
  const float sgw3 = SC[0], cb = SC[1];

#pragma unroll 1
  for (int it = 0; it < 6; ++it) {           // uniform trip count
    const int wt = blockIdx.x * 24 + it * 4 + wave;   // < 12240 always
    const int g0 = wt * 32;
    const int b = g0 / EDGES;                // 32 | EDGES: no batch crossing
    const int e0 = g0 - b * EDGES;
    const int bofs = (b << 9);

    // ---- stage 1: load h in A-frag layout; LN1 stats over qd-group ----
    float4 h4[2][4][2];
    float rs_m[2], nm_m[2];
#pragma unroll
    for (int mt = 0; mt < 2; ++mt) {
      const int2 ss = map[e0 + mt * 16 + cl];
      const float* pr = P + ((size_t)(bofs + ss.x) << 7) + qd * 8;
      const float* qr = Q + ((size_t)(bofs + ss.y) << 7) + qd * 8;
      float s1 = 0.f, q1 = 0.f;
#pragma unroll
      for (int kt = 0; kt < 4; ++kt) {
        const float4 pa = *(const float4*)(pr + kt * 32);
        const float4 pb = *(const float4*)(pr + kt * 32 + 4);
        const float4 qa = *(const float4*)(qr + kt * 32);
        const float4 qb = *(const float4*)(qr + kt * 32 + 4);
        float4 ha, hb;
        ha.x = fmaxf(pa.x + qa.x, 0.f); ha.y = fmaxf(pa.y + qa.y, 0.f);
        ha.z = fmaxf(pa.z + qa.z, 0.f); ha.w = fmaxf(pa.w + qa.w, 0.f);
        hb.x = fmaxf(pb.x + qb.x, 0.f); hb.y = fmaxf(pb.y + qb.y, 0.f);
        hb.z = fmaxf(pb.z + qb.z, 0.f); hb.w = fmaxf(pb.w + qb.w, 0.f);
        h4[mt][kt][0] = ha;
        h4[mt][kt][1] = hb;
        s1 += ((ha.x + ha.y) + (ha.z + ha.w)) + ((hb.x + hb.y) + (hb.z + hb.w));
        q1 = fmaf(ha.x, ha.x, q1); q1 = fmaf(ha.y, ha.y, q1);
        q1 = fmaf(ha.z, ha.z, q1); q1 = fmaf(ha.w, ha.w, q1);
        q1 = fmaf(hb.x, hb.x, q1); q1 = fmaf(hb.y, hb.y, q1);
        q1 = fmaf(hb.z, hb.z, q1); q1 = fmaf(hb.w, hb.w, q1);
      }
      // sum over the 4 qd-lanes holding this edge's k-slices
      s1 += __shfl_xor(s1, 16, 64);
      s1 += __shfl_xor(s1, 32, 64);
      q1 += __shfl_xor(q1, 16, 64);
      q1 += __shfl_xor(q1, 32, 64);
      const float mu = s1 * (1.0f / 128.0f);
      const float var = fmaxf(q1 * (1.0f / 128.0f) - mu * mu, 0.0f);
      const float rs = rsqrtf(var + 1e-5f);
      rs_m[mt] = rs;
      nm_m[mt] = -mu * rs;
    }

    // ---- stage 2: S = x̂ @ G via 3-product bf16-split MFMA ----
    f32x4 acc[2][8];
#pragma unroll
    for (int mt = 0; mt < 2; ++mt)
#pragma unroll
      for (int nt = 0; nt < 8; ++nt) acc[mt][nt] = (f32x4){0.f, 0.f, 0.f, 0.f};

#pragma unroll
    for (int kt = 0; kt < 4; ++kt) {
      s16x8 Bh[8], Bl[8];
#pragma unroll
      for (int nt = 0; nt < 8; ++nt) {
        const int fi = (kt * 8 + nt) * 64 + lane;
        Bh[nt] = sBH[fi];
        Bl[nt] = sBL[fi];
      }
      s16x8 Ah[2], Al[2];
#pragma unroll
      for (int mt = 0; mt < 2; ++mt) {
        const float4 u0 = h4[mt][kt][0];
        const float4 u1 = h4[mt][kt][1];
        const float uu[8] = {u0.x, u0.y, u0.z, u0.w, u1.x, u1.y, u1.z, u1.w};
#pragma unroll
        for (int j = 0; j < 8; ++j) {
          const float xh = fmaf(uu[j], rs_m[mt], nm_m[mt]);
          const uint32_t xu = __float_as_uint(xh);
          const float d = xh - __uint_as_float(xu & 0xFFFF0000u);
          Ah[mt][j] = (short)(xu >> 16);
          Al[mt][j] = (short)(__float_as_uint(d) >> 16);
        }
      }
#pragma unroll
      for (int nt = 0; nt < 8; ++nt) {
        acc[0][nt] = __builtin_amdgcn_mfma_f32_16x16x32_bf16(Ah[0], Bh[nt], acc[0][nt], 0, 0, 0);
        acc[1][nt] = __builtin_amdgcn_mfma_f32_16x16x32_bf16(Ah[1], Bh[nt], acc[1][nt], 0, 0, 0);
      }
#pragma unroll
      for (int nt = 0; nt < 8; ++nt) {
        acc[0][nt] = __builtin_amdgcn_mfma_f32_16x16x32_bf16(Al[0], Bh[nt], acc[0][nt], 0, 0, 0);
        acc[1][nt] = __builtin_amdgcn_mfma_f32_16x16x32_bf16(Al[1], Bh[nt], acc[1][nt], 0, 0, 0);
      }
#pragma unroll
      for (int nt = 0; nt < 8; ++nt) {
        acc[0][nt] = __builtin_amdgcn_mfma_f32_16x16x32_bf16(Ah[0], Bl[nt], acc[0][nt], 0, 0, 0);
        acc[1][nt] = __builtin_amdgcn_mfma_f32_16x16x32_bf16(Ah[1], Bl[nt], acc[1][nt], 0, 0, 0);
      }
    }

    // ---- epilogue: h2 = relu(S + SB[n]); folded LN2 + W3 (round-8 verified) --
#pragma unroll
    for (int mt = 0; mt < 2; ++mt) {
      float sr[4] = {0.f, 0.f, 0.f, 0.f};
      float qr[4] = {0.f, 0.f, 0.f, 0.f};
      float tr[4] = {0.f, 0.f, 0.f, 0.f};
#pragma unroll
      for (int nt = 0; nt < 8; ++nt) {
        const f32x4 a = acc[mt][nt];
#pragma unroll
        for (int r = 0; r < 4; ++r) {
          const float h2 = fmaxf(a[r] + SBv[nt], 0.f);
          sr[r] += h2;
          qr[r] = fmaf(h2, h2, qr[r]);
          tr[r] = fmaf(h2, GWv[nt], tr[r]);
        }
      }
#pragma unroll
      for (int r = 0; r < 4; ++r) {
        float s2 = sr[r], q2 = qr[r], t = tr[r];
#pragma unroll
        for (int off = 1; off < 16; off <<= 1) {
          s2 += __shfl_xor(s2, off, 64);
          q2 += __shfl_xor(q2, off, 64);
          t  += __shfl_xor(t,  off, 64);
        }
        if (cl == 0) {
          const float mu2 = s2 * (1.0f / 128.0f);
          const float var2 = fmaxf(q2 * (1.0f / 128.0f) - mu2 * mu2, 0.0f);
          const float rs2 = rsqrtf(var2 + 1e-5f);
          logits[g0 + mt * 16 + qd * 4 + r] = rs2 * (t - mu2 * sgw3) + cb;
        }
      }
    }
  }
}

// ---------------- gumbel argmax, stage 1: per-(bs,chunk) best ----------------
__global__ __launch_bounds__(256) void gumbel_kernel(
    const float* __restrict__ logits, float* __restrict__ bestval,
    int* __restrict__ bestidx) {
  const int bs = blockIdx.x / CHUNKS;     // b*5 + s
  const int chunk = blockIdx.x % CHUNKS;
  const int b = bs / NSAMP;
  const float* lg = logits + b * EDGES;
  float best = -1e30f; int bi = 0x7fffffff;
  for (int e = chunk * 256 + threadIdx.x; e < EDGES; e += CHUNKS * 256) {
    uint32_t n = (uint32_t)(bs * EDGES + e);
    float val = lg[e] + gumbel_valf(n);
    if (val > best) { best = val; bi = e; }
  }
  __shared__ float sv[256];
  __shared__ int si[256];
  sv[threadIdx.x] = best; si[threadIdx.x] = bi;
  __syncthreads();
  for (int off = 128; off; off >>= 1) {
    if (threadIdx.x < off) {
      float ov = sv[threadIdx.x + off]; int oi = si[threadIdx.x + off];
      if (ov > sv[threadIdx.x] ||
          (ov == sv[threadIdx.x] && oi < si[threadIdx.x])) {
        sv[threadIdx.x] = ov; si[threadIdx.x] = oi;
      }
    }
    __syncthreads();
  }
  if (threadIdx.x == 0) { bestval[blockIdx.x] = sv[0]; bestidx[blockIdx.x] = si[0]; }
}

// ---------------- gumbel argmax, stage 2: winner -> adj ----------------------
__global__ __launch_bounds__(64) void select_kernel(
    const float* __restrict__ bestval, const int* __restrict__ bestidx,
    const int2* __restrict__ map, float* __restrict__ adj) {
  const int bs = blockIdx.x;
  const int lane = threadIdx.x;
  float v = -1e30f; int idx = 0x7fffffff;
  if (lane < CHUNKS) { v = bestval[bs * CHUNKS + lane]; idx = bestidx[bs * CHUNKS + lane]; }
#pragma unroll
  for (int off = 32; off; off >>= 1) {
    float ov = __shfl_xor(v, off, 64);
    int oi = __shfl_xor(idx, off, 64);
    if (ov > v || (ov == v && oi < idx)) { v = ov; idx = oi; }
  }
  if (lane == 0) {
    int b = bs / NSAMP;
    int2 ss = map[idx];
    adj[((b * NNODES) + ss.x) * NNODES + ss.y] = 1.0f;
  }
}

extern "C" void kernel_launch(void* const* d_in, const int* in_sizes, int n_in,
                              void* d_out, int out_size, void* d_ws, size_t ws_size,
                              hipStream_t stream) {
  const float* nodes = (const float*)d_in[0];
  const float* W1  = (const float*)d_in[1];
  const float* b1  = (const float*)d_in[2];
  const float* g1  = (const float*)d_in[3];
  const float* be1 = (const float*)d_in[4];
  const float* W2  = (const float*)d_in[5];
  const float* b2  = (const float*)d_in[6];
  const float* g2  = (const float*)d_in[7];
  const float* be2 = (const float*)d_in[8];
  const float* W3  = (const float*)d_in[9];
  const float* b3  = (const float*)d_in[10];
  float* adj = (float*)d_out;

  char* ws = (char*)d_ws;
  float* P       = (float*)(ws);                       // 1 MB  [2048][128]
  float* Q       = (float*)(ws + (1 << 20));           // 1 MB
  int2*  map     = (int2*) (ws + (2 << 20));           // 783 KB
  float* logits  = (float*)(ws + (3 << 20));           // 1.57 MB
  unsigned short* GFH = (unsigned short*)(ws + (5 << 20));           // 32 KB
  unsigned short* GFL = (unsigned short*)(ws + (5 << 20) + 32768);   // 32 KB
  float* SB      = (float*)(ws + (5 << 20) + 66048);
  float* GW3     = (float*)(ws + (5 << 20) + 66560);
  float* SC      = (float*)(ws + (5 << 20) + 67072);
  float* bestval = (float*)(ws + (5 << 20) + 131072);  // 800*4
  int*   bestidx = (int*)  (ws + (5 << 20) + 137472);  // 800*4

  hipMemsetAsync(adj, 0, (size_t)out_size * sizeof(float), stream);
  setup_kernel<<<256 + MAP_BLOCKS + 1, 256, 0, stream>>>(
      nodes, W1, b1, W2, g1, be1, b2, g2, be2, W3, b3,
      P, Q, map, GFH, GFL, SB, GW3, SC);
  mlp_kernel<<<MLP_GRID, 256, 0, stream>>>(P, Q, map, GFH, GFL,
                                           SB, GW3, SC, logits);
  gumbel_kernel<<<20 * CHUNKS, 256, 0, stream>>>(logits, bestval, bestidx);
  select_kernel<<<20, 64, 0, stream>>>(bestval, bestidx, map, adj);
}

// Round 10
// 232.617 us; speedup vs baseline: 1.0118x; 1.0118x over previous
//
#include <hip/hip_runtime.h>
#include <stdint.h>

#define FEAT 128
#define NNODES 512
#define BATCH 4
#define EDGES 97920              // sum_{r=257}^{511} r ; 32 | EDGES
#define BE (BATCH*EDGES)         // 391680
#define NSAMP 5
#define BASE_OFF 32896           // 256*257/2
#define CHUNKS 40                // gumbel blocks per (b,s)
#define NWT (BE/32)              // 12240 wave-tiles (32 edges per wave)
#define MLP_GRID 510             // 510 x 4 waves x 6 tiles = 12240 exactly
#define MAP_BLOCKS 383           // ceil(EDGES/256)

typedef float f32x4 __attribute__((ext_vector_type(4)));
typedef short s16x8 __attribute__((ext_vector_type(8)));

// ---------------- threefry2x32 (exact JAX core, key=[0,42]) ------------------
__device__ __forceinline__ void threefry2x32(uint32_t k0, uint32_t k1,
                                             uint32_t& x0, uint32_t& x1) {
  uint32_t k2 = k0 ^ k1 ^ 0x1BD11BDAu;
  x0 += k0; x1 += k1;
#define RR(r) { x0 += x1; x1 = (x1 << (r)) | (x1 >> (32 - (r))); x1 ^= x0; }
  RR(13) RR(15) RR(26) RR(6)   x0 += k1; x1 += k2 + 1u;
  RR(17) RR(29) RR(16) RR(24)  x0 += k2; x1 += k0 + 2u;
  RR(13) RR(15) RR(26) RR(6)   x0 += k0; x1 += k1 + 3u;
  RR(17) RR(29) RR(16) RR(24)  x0 += k1; x1 += k2 + 4u;
  RR(13) RR(15) RR(26) RR(6)   x0 += k2; x1 += k0 + 5u;
#undef RR
}

// partitionable threefry gumbel, fp32 logs (verified passing rounds 7-9)
__device__ __forceinline__ float gumbel_valf(uint32_t n) {
  uint32_t x0 = 0u, x1 = n;
  threefry2x32(0u, 42u, x0, x1);
  uint32_t bits = x0 ^ x1;
  uint32_t fb = (bits >> 9) | 0x3f800000u;
  float f = __uint_as_float(fb) - 1.0f;
  float u = fmaxf(f, 1.1754943508222875e-38f);
  return -logf(-logf(u));
}

// ---------------- fused setup: pq (blk<256) | map (256..638) | prep (639) ----
__global__ __launch_bounds__(256) void setup_kernel(
    const float* __restrict__ nodes, const float* __restrict__ W1,
    const float* __restrict__ b1, const float* __restrict__ W2,
    const float* __restrict__ g1, const float* __restrict__ be1,
    const float* __restrict__ b2, const float* __restrict__ g2,
    const float* __restrict__ be2, const float* __restrict__ W3,
    const float* __restrict__ b3, float* __restrict__ P, float* __restrict__ Q,
    int2* __restrict__ map, unsigned short* __restrict__ GFH,
    unsigned short* __restrict__ GFL, float* __restrict__ SB,
    float* __restrict__ GW3, float* __restrict__ SC) {
  const int blk = blockIdx.x;
  const int tid = threadIdx.x;
  if (blk < 256) {
    // ---- pq: P = nodes @ W1_top + b1, Q = nodes @ W1_bot, row-major ----
    __shared__ float snode[8][FEAT];
    const int row0 = blk * 8;
    for (int i = tid; i < 8 * FEAT; i += 256)
      snode[i >> 7][i & 127] = nodes[row0 * FEAT + i];
    __syncthreads();
    const int j = tid & 127;
    const int half = tid >> 7;
    const float* w = W1 + half * FEAT * FEAT + j;
    float acc[8] = {0, 0, 0, 0, 0, 0, 0, 0};
    for (int k = 0; k < FEAT; ++k) {
      float wv = w[k * FEAT];
#pragma unroll
      for (int m = 0; m < 8; ++m) acc[m] += snode[m][k] * wv;
    }
    const float bv = half ? 0.0f : b1[j];
    float* out = half ? Q : P;
#pragma unroll
    for (int m = 0; m < 8; ++m) out[(row0 + m) * FEAT + j] = acc[m] + bv;
  } else if (blk < 256 + MAP_BLOCKS) {
    // ---- map: edge -> (sink, src) ----
    int e = (blk - 256) * 256 + tid;
    if (e < EDGES) {
      double x = (double)(e + BASE_OFF);
      int s = (int)((1.0 + sqrt(1.0 + 8.0 * x)) * 0.5);
      while ((long long)s * (s - 1) / 2 - BASE_OFF > e) --s;
      while ((long long)(s + 1) * s / 2 - BASE_OFF <= e) ++s;
      int src = e - (int)((long long)s * (s - 1) / 2 - BASE_OFF);
      map[e] = make_int2(s, src);
    }
  } else {
    // ---- prep: B-fragments of G = g1*W2 in bf16 hi/lo + SB/GW3/SC ----
    // GF*[(kt*8+nt)*64+lane][j] = bf16(G[k][n]), n=nt*16+(lane&15),
    // k=kt*32+(lane>>4)*8+j   (verified rounds 8-9)
    for (int idx = tid; idx < FEAT * FEAT; idx += 256) {
      const int j = idx & 7;
      const int lane = (idx >> 3) & 63;
      const int nt = (idx >> 9) & 7;
      const int kt = (idx >> 12) & 3;
      const int n = nt * 16 + (lane & 15);
      const int k = kt * 32 + ((lane >> 4) << 3) + j;
      const float g = g1[k] * W2[k * FEAT + n];
      const uint32_t gu = __float_as_uint(g);
      const float d = g - __uint_as_float(gu & 0xFFFF0000u);
      GFH[idx] = (unsigned short)(gu >> 16);
      GFL[idx] = (unsigned short)(__float_as_uint(d) >> 16);
    }
    if (tid < FEAT) {
      float sb = 0.f;
      for (int k = 0; k < FEAT; ++k)
        sb = fmaf(be1[k], W2[k * FEAT + tid], sb);
      SB[tid] = sb + b2[tid];
      GW3[tid] = g2[tid] * W3[tid];
    }
    __syncthreads();
    if (tid == 0) {
      float a = 0.f, c = 0.f;
      for (int n = 0; n < FEAT; ++n) { a += GW3[n]; c = fmaf(be2[n], W3[n], c); }
      SC[0] = a; SC[1] = c + b3[0];
    }
  }
}

// ---------------- main MLP kernel (MFMA, register-budgeted) -------------------
// Same math as round 9 (verified). Register fix: A is converted to bf16 hi/lo
// fragments IMMEDIATELY after LN1 stats (h never live across the MFMA loop),
// and B streams from LDS two nt-fragments at a time (32 VGPRs, not 128).
// Steady live set ~130 arch VGPR + 64 AGPR => no scratch spills.
__global__ __launch_bounds__(256, 2) void mlp_kernel(
    const float* __restrict__ P, const float* __restrict__ Q,
    const int2* __restrict__ map,
    const unsigned short* __restrict__ GFH,
    const unsigned short* __restrict__ GFL,
    const float* __restrict__ SB, const float* __restrict__ GW3,
    const float* __restrict__ SC, float* __restrict__ logits) {
  __shared__ s16x8 sBH[2048];                // 32 KB
  __shared__ s16x8 sBL[2048];                // 32 KB
  const int tid = threadIdx.x;
  const int lane = tid & 63;
  const int wave = tid >> 6;
  const int cl = lane & 15;                   // C/D col lane; A m-row lane
  const int qd = lane >> 4;                   // quad: A k-group, C/D row group

  {
    const float4* s1 = (const float4*)GFH;
    const float4* s2 = (const float4*)GFL;
    float4* d1 = (float4*)sBH;
    float4* d2 = (float4*)sBL;
    for (int i = tid; i < 2048; i += 256) { d1[i] = s1[i]; d2[i] = s2[i]; }
  }
  __syncthreads();

  float SBv[8], GWv[8];
#pragma unroll
  for (int nt = 0; nt < 8; ++nt) {
    SBv[nt] = SB[nt * 16 + cl];
    GWv[nt] = GW3[nt * 16 + cl];
  }
  const float sgw3 = SC[0], cb = SC[1];

#pragma unroll 1
  for (int it = 0; it < 6; ++it) {           // uniform trip count
    const int wt = blockIdx.x * 24 + it * 4 + wave;   // < 12240 always
    const int g0 = wt * 32;
    const int b = g0 / EDGES;                // 32 | EDGES: no batch crossing
    const int e0 = g0 - b * EDGES;
    const int bofs = (b << 9);

    // ---- stage 1: h in A-frag layout -> LN1 stats -> bf16 hi/lo frags ----
    s16x8 Ah[2][4], Al[2][4];
#pragma unroll
    for (int mt = 0; mt < 2; ++mt) {
      const int2 ss = map[e0 + mt * 16 + cl];
      const float* pr = P + ((size_t)(bofs + ss.x) << 7) + qd * 8;
      const float* qr = Q + ((size_t)(bofs + ss.y) << 7) + qd * 8;
      float4 hv[8];                           // transient: this mt only
      float s1 = 0.f, q1 = 0.f;
#pragma unroll
      for (int kt = 0; kt < 4; ++kt) {
        const float4 pa = *(const float4*)(pr + kt * 32);
        const float4 pb = *(const float4*)(pr + kt * 32 + 4);
        const float4 qa = *(const float4*)(qr + kt * 32);
        const float4 qb = *(const float4*)(qr + kt * 32 + 4);
        float4 ha, hb;
        ha.x = fmaxf(pa.x + qa.x, 0.f); ha.y = fmaxf(pa.y + qa.y, 0.f);
        ha.z = fmaxf(pa.z + qa.z, 0.f); ha.w = fmaxf(pa.w + qa.w, 0.f);
        hb.x = fmaxf(pb.x + qb.x, 0.f); hb.y = fmaxf(pb.y + qb.y, 0.f);
        hb.z = fmaxf(pb.z + qb.z, 0.f); hb.w = fmaxf(pb.w + qb.w, 0.f);
        hv[kt * 2] = ha;
        hv[kt * 2 + 1] = hb;
        s1 += ((ha.x + ha.y) + (ha.z + ha.w)) + ((hb.x + hb.y) + (hb.z + hb.w));
        q1 = fmaf(ha.x, ha.x, q1); q1 = fmaf(ha.y, ha.y, q1);
        q1 = fmaf(ha.z, ha.z, q1); q1 = fmaf(ha.w, ha.w, q1);
        q1 = fmaf(hb.x, hb.x, q1); q1 = fmaf(hb.y, hb.y, q1);
        q1 = fmaf(hb.z, hb.z, q1); q1 = fmaf(hb.w, hb.w, q1);
      }
      s1 += __shfl_xor(s1, 16, 64);
      s1 += __shfl_xor(s1, 32, 64);
      q1 += __shfl_xor(q1, 16, 64);
      q1 += __shfl_xor(q1, 32, 64);
      const float mu = s1 * (1.0f / 128.0f);
      const float var = fmaxf(q1 * (1.0f / 128.0f) - mu * mu, 0.0f);
      const float rs = rsqrtf(var + 1e-5f);
      const float nm = -mu * rs;
      // normalize + bf16 hi/lo split (identical numerics to round 9)
#pragma unroll
      for (int kt = 0; kt < 4; ++kt) {
        const float4 u0 = hv[kt * 2];
        const float4 u1 = hv[kt * 2 + 1];
        const float uu[8] = {u0.x, u0.y, u0.z, u0.w, u1.x, u1.y, u1.z, u1.w};
#pragma unroll
        for (int j = 0; j < 8; ++j) {
          const float xh = fmaf(uu[j], rs, nm);
          const uint32_t xu = __float_as_uint(xh);
          const float d = xh - __uint_as_float(xu & 0xFFFF0000u);
          Ah[mt][kt][j] = (short)(xu >> 16);
          Al[mt][kt][j] = (short)(__float_as_uint(d) >> 16);
        }
      }
    }

    // ---- stage 2: 3-product bf16-split MFMA; B streamed 2 nt at a time ----
    f32x4 acc[2][8];
#pragma unroll
    for (int mt = 0; mt < 2; ++mt)
#pragma unroll
      for (int nt = 0; nt < 8; ++nt) acc[mt][nt] = (f32x4){0.f, 0.f, 0.f, 0.f};

#pragma unroll
    for (int kt = 0; kt < 4; ++kt) {
#pragma unroll
      for (int np = 0; np < 4; ++np) {        // nt pair: 2*np, 2*np+1
        const int n0 = 2 * np, n1 = 2 * np + 1;
        const s16x8 Bh0 = sBH[(kt * 8 + n0) * 64 + lane];
        const s16x8 Bl0 = sBL[(kt * 8 + n0) * 64 + lane];
        const s16x8 Bh1 = sBH[(kt * 8 + n1) * 64 + lane];
        const s16x8 Bl1 = sBL[(kt * 8 + n1) * 64 + lane];
        // dependent MFMAs on the same acc are 4 issues apart
        acc[0][n0] = __builtin_amdgcn_mfma_f32_16x16x32_bf16(Ah[0][kt], Bh0, acc[0][n0], 0, 0, 0);
        acc[1][n0] = __builtin_amdgcn_mfma_f32_16x16x32_bf16(Ah[1][kt], Bh0, acc[1][n0], 0, 0, 0);
        acc[0][n1] = __builtin_amdgcn_mfma_f32_16x16x32_bf16(Ah[0][kt], Bh1, acc[0][n1], 0, 0, 0);
        acc[1][n1] = __builtin_amdgcn_mfma_f32_16x16x32_bf16(Ah[1][kt], Bh1, acc[1][n1], 0, 0, 0);
        acc[0][n0] = __builtin_amdgcn_mfma_f32_16x16x32_bf16(Al[0][kt], Bh0, acc[0][n0], 0, 0, 0);
        acc[1][n0] = __builtin_amdgcn_mfma_f32_16x16x32_bf16(Al[1][kt], Bh0, acc[1][n0], 0, 0, 0);
        acc[0][n1] = __builtin_amdgcn_mfma_f32_16x16x32_bf16(Al[0][kt], Bh1, acc[0][n1], 0, 0, 0);
        acc[1][n1] = __builtin_amdgcn_mfma_f32_16x16x32_bf16(Al[1][kt], Bh1, acc[1][n1], 0, 0, 0);
        acc[0][n0] = __builtin_amdgcn_mfma_f32_16x16x32_bf16(Ah[0][kt], Bl0, acc[0][n0], 0, 0, 0);
        acc[1][n0] = __builtin_amdgcn_mfma_f32_16x16x32_bf16(Ah[1][kt], Bl0, acc[1][n0], 0, 0, 0);
        acc[0][n1] = __builtin_amdgcn_mfma_f32_16x16x32_bf16(Ah[0][kt], Bl1, acc[0][n1], 0, 0, 0);
        acc[1][n1] = __builtin_amdgcn_mfma_f32_16x16x32_bf16(Ah[1][kt], Bl1, acc[1][n1], 0, 0, 0);
      }
    }

    // ---- epilogue: h2 = relu(S + SB[n]); folded LN2 + W3 (verified) ----
#pragma unroll
    for (int mt = 0; mt < 2; ++mt) {
      float sr[4] = {0.f, 0.f, 0.f, 0.f};
      float qr[4] = {0.f, 0.f, 0.f, 0.f};
      float tr[4] = {0.f, 0.f, 0.f, 0.f};
#pragma unroll
      for (int nt = 0; nt < 8; ++nt) {
        const f32x4 a = acc[mt][nt];
#pragma unroll
        for (int r = 0; r < 4; ++r) {
          const float h2 = fmaxf(a[r] + SBv[nt], 0.f);
          sr[r] += h2;
          qr[r] = fmaf(h2, h2, qr[r]);
          tr[r] = fmaf(h2, GWv[nt], tr[r]);
        }
      }
#pragma unroll
      for (int r = 0; r < 4; ++r) {
        float s2 = sr[r], q2 = qr[r], t = tr[r];
#pragma unroll
        for (int off = 1; off < 16; off <<= 1) {
          s2 += __shfl_xor(s2, off, 64);
          q2 += __shfl_xor(q2, off, 64);
          t  += __shfl_xor(t,  off, 64);
        }
        if (cl == 0) {
          const float mu2 = s2 * (1.0f / 128.0f);
          const float var2 = fmaxf(q2 * (1.0f / 128.0f) - mu2 * mu2, 0.0f);
          const float rs2 = rsqrtf(var2 + 1e-5f);
          logits[g0 + mt * 16 + qd * 4 + r] = rs2 * (t - mu2 * sgw3) + cb;
        }
      }
    }
  }
}

// ---------------- gumbel argmax, stage 1: per-(bs,chunk) best ----------------
__global__ __launch_bounds__(256) void gumbel_kernel(
    const float* __restrict__ logits, float* __restrict__ bestval,
    int* __restrict__ bestidx) {
  const int bs = blockIdx.x / CHUNKS;     // b*5 + s
  const int chunk = blockIdx.x % CHUNKS;
  const int b = bs / NSAMP;
  const float* lg = logits + b * EDGES;
  float best = -1e30f; int bi = 0x7fffffff;
  for (int e = chunk * 256 + threadIdx.x; e < EDGES; e += CHUNKS * 256) {
    uint32_t n = (uint32_t)(bs * EDGES + e);
    float val = lg[e] + gumbel_valf(n);
    if (val > best) { best = val; bi = e; }
  }
  __shared__ float sv[256];
  __shared__ int si[256];
  sv[threadIdx.x] = best; si[threadIdx.x] = bi;
  __syncthreads();
  for (int off = 128; off; off >>= 1) {
    if (threadIdx.x < off) {
      float ov = sv[threadIdx.x + off]; int oi = si[threadIdx.x + off];
      if (ov > sv[threadIdx.x] ||
          (ov == sv[threadIdx.x] && oi < si[threadIdx.x])) {
        sv[threadIdx.x] = ov; si[threadIdx.x] = oi;
      }
    }
    __syncthreads();
  }
  if (threadIdx.x == 0) { bestval[blockIdx.x] = sv[0]; bestidx[blockIdx.x] = si[0]; }
}

// ---------------- gumbel argmax, stage 2: winner -> adj ----------------------
__global__ __launch_bounds__(64) void select_kernel(
    const float* __restrict__ bestval, const int* __restrict__ bestidx,
    const int2* __restrict__ map, float* __restrict__ adj) {
  const int bs = blockIdx.x;
  const int lane = threadIdx.x;
  float v = -1e30f; int idx = 0x7fffffff;
  if (lane < CHUNKS) { v = bestval[bs * CHUNKS + lane]; idx = bestidx[bs * CHUNKS + lane]; }
#pragma unroll
  for (int off = 32; off; off >>= 1) {
    float ov = __shfl_xor(v, off, 64);
    int oi = __shfl_xor(idx, off, 64);
    if (ov > v || (ov == v && oi < idx)) { v = ov; idx = oi; }
  }
  if (lane == 0) {
    int b = bs / NSAMP;
    int2 ss = map[idx];
    adj[((b * NNODES) + ss.x) * NNODES + ss.y] = 1.0f;
  }
}

extern "C" void kernel_launch(void* const* d_in, const int* in_sizes, int n_in,
                              void* d_out, int out_size, void* d_ws, size_t ws_size,
                              hipStream_t stream) {
  const float* nodes = (const float*)d_in[0];
  const float* W1  = (const float*)d_in[1];
  const float* b1  = (const float*)d_in[2];
  const float* g1  = (const float*)d_in[3];
  const float* be1 = (const float*)d_in[4];
  const float* W2  = (const float*)d_in[5];
  const float* b2  = (const float*)d_in[6];
  const float* g2  = (const float*)d_in[7];
  const float* be2 = (const float*)d_in[8];
  const float* W3  = (const float*)d_in[9];
  const float* b3  = (const float*)d_in[10];
  float* adj = (float*)d_out;

  char* ws = (char*)d_ws;
  float* P       = (float*)(ws);                       // 1 MB  [2048][128]
  float* Q       = (float*)(ws + (1 << 20));           // 1 MB
  int2*  map     = (int2*) (ws + (2 << 20));           // 783 KB
  float* logits  = (float*)(ws + (3 << 20));           // 1.57 MB
  unsigned short* GFH = (unsigned short*)(ws + (5 << 20));           // 32 KB
  unsigned short* GFL = (unsigned short*)(ws + (5 << 20) + 32768);   // 32 KB
  float* SB      = (float*)(ws + (5 << 20) + 66048);
  float* GW3     = (float*)(ws + (5 << 20) + 66560);
  float* SC      = (float*)(ws + (5 << 20) + 67072);
  float* bestval = (float*)(ws + (5 << 20) + 131072);  // 800*4
  int*   bestidx = (int*)  (ws + (5 << 20) + 137472);  // 800*4

  hipMemsetAsync(adj, 0, (size_t)out_size * sizeof(float), stream);
  setup_kernel<<<256 + MAP_BLOCKS + 1, 256, 0, stream>>>(
      nodes, W1, b1, W2, g1, be1, b2, g2, be2, W3, b3,
      P, Q, map, GFH, GFL, SB, GW3, SC);
  mlp_kernel<<<MLP_GRID, 256, 0, stream>>>(P, Q, map, GFH, GFL,
                                           SB, GW3, SC, logits);
  gumbel_kernel<<<20 * CHUNKS, 256, 0, stream>>>(logits, bestval, bestidx);
  select_kernel<<<20, 64, 0, stream>>>(bestval, bestidx, map, adj);
}

// Round 11
// 172.235 us; speedup vs baseline: 1.3665x; 1.3506x over previous
//
#include <hip/hip_runtime.h>
#include <stdint.h>

#define FEAT 128
#define NNODES 512
#define BATCH 4
#define EDGES 97920              // sum_{r=257}^{511} r ; 32 | EDGES
#define BE (BATCH*EDGES)         // 391680
#define NSAMP 5
#define BASE_OFF 32896           // 256*257/2
#define CHUNKS 40                // gumbel blocks per (b,s)
#define NWT (BE/32)              // 12240 wave-tiles (32 edges per wave)
#define MLP_GRID 510             // 510 x 4 waves x 6 tiles = 12240 exactly
#define MAP_BLOCKS 383           // ceil(EDGES/256)

typedef float f32x4 __attribute__((ext_vector_type(4)));
typedef short s16x8 __attribute__((ext_vector_type(8)));

// ---------------- threefry2x32 (exact JAX core, key=[0,42]) ------------------
__device__ __forceinline__ void threefry2x32(uint32_t k0, uint32_t k1,
                                             uint32_t& x0, uint32_t& x1) {
  uint32_t k2 = k0 ^ k1 ^ 0x1BD11BDAu;
  x0 += k0; x1 += k1;
#define RR(r) { x0 += x1; x1 = (x1 << (r)) | (x1 >> (32 - (r))); x1 ^= x0; }
  RR(13) RR(15) RR(26) RR(6)   x0 += k1; x1 += k2 + 1u;
  RR(17) RR(29) RR(16) RR(24)  x0 += k2; x1 += k0 + 2u;
  RR(13) RR(15) RR(26) RR(6)   x0 += k0; x1 += k1 + 3u;
  RR(17) RR(29) RR(16) RR(24)  x0 += k1; x1 += k2 + 4u;
  RR(13) RR(15) RR(26) RR(6)   x0 += k2; x1 += k0 + 5u;
#undef RR
}

// partitionable threefry gumbel, fp32 logs (verified passing rounds 7-10)
__device__ __forceinline__ float gumbel_valf(uint32_t n) {
  uint32_t x0 = 0u, x1 = n;
  threefry2x32(0u, 42u, x0, x1);
  uint32_t bits = x0 ^ x1;
  uint32_t fb = (bits >> 9) | 0x3f800000u;
  float f = __uint_as_float(fb) - 1.0f;
  float u = fmaxf(f, 1.1754943508222875e-38f);
  return -logf(-logf(u));
}

// ---------------- fused setup: pq (blk<256) | map (256..638) | prep (639) ----
__global__ __launch_bounds__(256) void setup_kernel(
    const float* __restrict__ nodes, const float* __restrict__ W1,
    const float* __restrict__ b1, const float* __restrict__ W2,
    const float* __restrict__ g1, const float* __restrict__ be1,
    const float* __restrict__ b2, const float* __restrict__ g2,
    const float* __restrict__ be2, const float* __restrict__ W3,
    const float* __restrict__ b3, float* __restrict__ P, float* __restrict__ Q,
    int2* __restrict__ map, unsigned short* __restrict__ GFH,
    unsigned short* __restrict__ GFL, float* __restrict__ SG,
    float* __restrict__ SB, float* __restrict__ GW3, float* __restrict__ SC) {
  const int blk = blockIdx.x;
  const int tid = threadIdx.x;
  if (blk < 256) {
    // ---- pq: P = nodes @ W1_top + b1, Q = nodes @ W1_bot, row-major ----
    __shared__ float snode[8][FEAT];
    const int row0 = blk * 8;
    for (int i = tid; i < 8 * FEAT; i += 256)
      snode[i >> 7][i & 127] = nodes[row0 * FEAT + i];
    __syncthreads();
    const int j = tid & 127;
    const int half = tid >> 7;
    const float* w = W1 + half * FEAT * FEAT + j;
    float acc[8] = {0, 0, 0, 0, 0, 0, 0, 0};
    for (int k = 0; k < FEAT; ++k) {
      float wv = w[k * FEAT];
#pragma unroll
      for (int m = 0; m < 8; ++m) acc[m] += snode[m][k] * wv;
    }
    const float bv = half ? 0.0f : b1[j];
    float* out = half ? Q : P;
#pragma unroll
    for (int m = 0; m < 8; ++m) out[(row0 + m) * FEAT + j] = acc[m] + bv;
  } else if (blk < 256 + MAP_BLOCKS) {
    // ---- map: edge -> (sink, src) ----
    int e = (blk - 256) * 256 + tid;
    if (e < EDGES) {
      double x = (double)(e + BASE_OFF);
      int s = (int)((1.0 + sqrt(1.0 + 8.0 * x)) * 0.5);
      while ((long long)s * (s - 1) / 2 - BASE_OFF > e) --s;
      while ((long long)(s + 1) * s / 2 - BASE_OFF <= e) ++s;
      int src = e - (int)((long long)s * (s - 1) / 2 - BASE_OFF);
      map[e] = make_int2(s, src);
    }
  } else {
    // ---- prep: B-fragments of G = g1*W2 in bf16 hi/lo + SG/SB/GW3/SC ----
    // GF*[(kt*8+nt)*64+lane][j] = bf16(G[k][n]), n=nt*16+(lane&15),
    // k=kt*32+(lane>>4)*8+j   (verified rounds 8-10)
    for (int idx = tid; idx < FEAT * FEAT; idx += 256) {
      const int j = idx & 7;
      const int lane = (idx >> 3) & 63;
      const int nt = (idx >> 9) & 7;
      const int kt = (idx >> 12) & 3;
      const int n = nt * 16 + (lane & 15);
      const int k = kt * 32 + ((lane >> 4) << 3) + j;
      const float g = g1[k] * W2[k * FEAT + n];
      const uint32_t gu = __float_as_uint(g);
      const float d = g - __uint_as_float(gu & 0xFFFF0000u);
      GFH[idx] = (unsigned short)(gu >> 16);
      GFL[idx] = (unsigned short)(__float_as_uint(d) >> 16);
    }
    if (tid < FEAT) {
      float sg = 0.f, sb = 0.f;
      for (int k = 0; k < FEAT; ++k) {
        const float w = W2[k * FEAT + tid];
        sg = fmaf(g1[k], w, sg);
        sb = fmaf(be1[k], w, sb);
      }
      SG[tid] = sg;
      SB[tid] = sb + b2[tid];
      GW3[tid] = g2[tid] * W3[tid];
    }
    __syncthreads();
    if (tid == 0) {
      float a = 0.f, c = 0.f;
      for (int n = 0; n < FEAT; ++n) { a += GW3[n]; c = fmaf(be2[n], W3[n], c); }
      SC[0] = a; SC[1] = c + b3[0];
    }
  }
}

// ---------------- main MLP kernel (MFMA, anti-spill) --------------------------
// Key change vs rounds 8-10: LN1 is folded into the EPILOGUE (round-3..7
// verified algebra): A-frags are bf16 hi/lo of RAW h built immediately at
// load (no fp32 h tile live), stats ride as 2 scalars per mt and finalize
// after the MFMAs. sched_barrier(0) fences stop the scheduler from hoisting
// loads into a giant live set (the root cause of rounds 8-10's 100 MB spills).
__global__ __launch_bounds__(256, 2) void mlp_kernel(
    const float* __restrict__ P, const float* __restrict__ Q,
    const int2* __restrict__ map,
    const unsigned short* __restrict__ GFH,
    const unsigned short* __restrict__ GFL,
    const float* __restrict__ SG, const float* __restrict__ SB,
    const float* __restrict__ GW3, const float* __restrict__ SC,
    float* __restrict__ logits) {
  __shared__ s16x8 sBH[2048];                // 32 KB
  __shared__ s16x8 sBL[2048];                // 32 KB
  const int tid = threadIdx.x;
  const int lane = tid & 63;
  const int wave = tid >> 6;
  const int cl = lane & 15;                   // C/D col lane; A m-row lane
  const int qd = lane >> 4;                   // quad: A k-group, C/D row group

  {
    const float4* s1p = (const float4*)GFH;
    const float4* s2p = (const float4*)GFL;
    float4* d1 = (float4*)sBH;
    float4* d2 = (float4*)sBL;
    for (int i = tid; i < 2048; i += 256) { d1[i] = s1p[i]; d2[i] = s2p[i]; }
  }
  __syncthreads();

  const float sgw3 = SC[0], cb = SC[1];

#pragma unroll 1
  for (int it = 0; it < 6; ++it) {           // uniform trip count
    const int wt = blockIdx.x * 24 + it * 4 + wave;   // < 12240 always
    const int g0 = wt * 32;
    const int b = g0 / EDGES;                // 32 | EDGES: no batch crossing
    const int e0 = g0 - b * EDGES;
    const int bofs = (b << 9);

    // ---- stage 1: raw h -> bf16 hi/lo A-frags at load; stats as partials ----
    s16x8 Ah[2][4], Al[2][4];
    float s1v[2], q1v[2];
#pragma unroll
    for (int mt = 0; mt < 2; ++mt) {
      const int2 ss = map[e0 + mt * 16 + cl];
      const float* pr = P + ((size_t)(bofs + ss.x) << 7) + qd * 8;
      const float* qr = Q + ((size_t)(bofs + ss.y) << 7) + qd * 8;
      float s1 = 0.f, q1 = 0.f;
#pragma unroll
      for (int kt = 0; kt < 4; ++kt) {
        const float4 pa = *(const float4*)(pr + kt * 32);
        const float4 pb = *(const float4*)(pr + kt * 32 + 4);
        const float4 qa = *(const float4*)(qr + kt * 32);
        const float4 qb = *(const float4*)(qr + kt * 32 + 4);
        const float uu[8] = {
            fmaxf(pa.x + qa.x, 0.f), fmaxf(pa.y + qa.y, 0.f),
            fmaxf(pa.z + qa.z, 0.f), fmaxf(pa.w + qa.w, 0.f),
            fmaxf(pb.x + qb.x, 0.f), fmaxf(pb.y + qb.y, 0.f),
            fmaxf(pb.z + qb.z, 0.f), fmaxf(pb.w + qb.w, 0.f)};
#pragma unroll
        for (int j = 0; j < 8; ++j) {
          const float h = uu[j];
          s1 += h;
          q1 = fmaf(h, h, q1);
          const uint32_t xu = __float_as_uint(h);
          const float d = h - __uint_as_float(xu & 0xFFFF0000u);
          Ah[mt][kt][j] = (short)(xu >> 16);
          Al[mt][kt][j] = (short)(__float_as_uint(d) >> 16);
        }
      }
      s1v[mt] = s1;
      q1v[mt] = q1;
      __builtin_amdgcn_sched_barrier(0);     // cap in-flight loads per mt
    }

    // ---- stage 2: 3-product bf16-split MFMA; B 2 nt-frags at a time ----
    f32x4 acc[2][8];
#pragma unroll
    for (int mt = 0; mt < 2; ++mt)
#pragma unroll
      for (int nt = 0; nt < 8; ++nt) acc[mt][nt] = (f32x4){0.f, 0.f, 0.f, 0.f};

#pragma unroll
    for (int kt = 0; kt < 4; ++kt) {
#pragma unroll
      for (int np = 0; np < 4; ++np) {        // nt pair: 2*np, 2*np+1
        const int n0 = 2 * np, n1 = 2 * np + 1;
        const s16x8 Bh0 = sBH[(kt * 8 + n0) * 64 + lane];
        const s16x8 Bl0 = sBL[(kt * 8 + n0) * 64 + lane];
        const s16x8 Bh1 = sBH[(kt * 8 + n1) * 64 + lane];
        const s16x8 Bl1 = sBL[(kt * 8 + n1) * 64 + lane];
        acc[0][n0] = __builtin_amdgcn_mfma_f32_16x16x32_bf16(Ah[0][kt], Bh0, acc[0][n0], 0, 0, 0);
        acc[1][n0] = __builtin_amdgcn_mfma_f32_16x16x32_bf16(Ah[1][kt], Bh0, acc[1][n0], 0, 0, 0);
        acc[0][n1] = __builtin_amdgcn_mfma_f32_16x16x32_bf16(Ah[0][kt], Bh1, acc[0][n1], 0, 0, 0);
        acc[1][n1] = __builtin_amdgcn_mfma_f32_16x16x32_bf16(Ah[1][kt], Bh1, acc[1][n1], 0, 0, 0);
        acc[0][n0] = __builtin_amdgcn_mfma_f32_16x16x32_bf16(Al[0][kt], Bh0, acc[0][n0], 0, 0, 0);
        acc[1][n0] = __builtin_amdgcn_mfma_f32_16x16x32_bf16(Al[1][kt], Bh0, acc[1][n0], 0, 0, 0);
        acc[0][n1] = __builtin_amdgcn_mfma_f32_16x16x32_bf16(Al[0][kt], Bh1, acc[0][n1], 0, 0, 0);
        acc[1][n1] = __builtin_amdgcn_mfma_f32_16x16x32_bf16(Al[1][kt], Bh1, acc[1][n1], 0, 0, 0);
        acc[0][n0] = __builtin_amdgcn_mfma_f32_16x16x32_bf16(Ah[0][kt], Bl0, acc[0][n0], 0, 0, 0);
        acc[1][n0] = __builtin_amdgcn_mfma_f32_16x16x32_bf16(Ah[1][kt], Bl0, acc[1][n0], 0, 0, 0);
        acc[0][n1] = __builtin_amdgcn_mfma_f32_16x16x32_bf16(Ah[0][kt], Bl1, acc[0][n1], 0, 0, 0);
        acc[1][n1] = __builtin_amdgcn_mfma_f32_16x16x32_bf16(Ah[1][kt], Bl1, acc[1][n1], 0, 0, 0);
        __builtin_amdgcn_sched_barrier(0);   // cap in-flight B frags
      }
    }

    // ---- finalize LN1 stats (post-MFMA) ----
    float mu[2], rs[2];
#pragma unroll
    for (int mt = 0; mt < 2; ++mt) {
      float s1 = s1v[mt], q1 = q1v[mt];
      s1 += __shfl_xor(s1, 16, 64);
      s1 += __shfl_xor(s1, 32, 64);
      q1 += __shfl_xor(q1, 16, 64);
      q1 += __shfl_xor(q1, 32, 64);
      mu[mt] = s1 * (1.0f / 128.0f);
      const float var = fmaxf(q1 * (1.0f / 128.0f) - mu[mt] * mu[mt], 0.0f);
      rs[mt] = rsqrtf(var + 1e-5f);
    }

    // ---- epilogue: LN1 fold (round-3..7 verified), relu, LN2+W3 fold ----
    // per-n constants via opaque offset so they can't become loop invariants
    int zz;
    asm volatile("v_mov_b32 %0, 0" : "=v"(zz));
    float SGn[8], SBn[8], GWn[8];
#pragma unroll
    for (int nt = 0; nt < 8; ++nt) {
      const int n = nt * 16 + cl + zz;
      SGn[nt] = SG[n];
      SBn[nt] = SB[n];
      GWn[nt] = GW3[n];
    }
#pragma unroll
    for (int mt = 0; mt < 2; ++mt) {
#pragma unroll
      for (int r = 0; r < 4; ++r) {
        const int me = qd * 4 + r;            // edge row within mt-tile
        const float mue = __shfl(mu[mt], me, 64);
        const float rse = __shfl(rs[mt], me, 64);
        float s2 = 0.f, q2 = 0.f, t = 0.f;
#pragma unroll
        for (int nt = 0; nt < 8; ++nt) {
          const float Sraw = acc[mt][nt][r];
          const float z = fmaf(rse, fmaf(-mue, SGn[nt], Sraw), SBn[nt]);
          const float h2 = fmaxf(z, 0.f);
          s2 += h2;
          q2 = fmaf(h2, h2, q2);
          t = fmaf(h2, GWn[nt], t);
        }
#pragma unroll
        for (int off = 1; off < 16; off <<= 1) {
          s2 += __shfl_xor(s2, off, 64);
          q2 += __shfl_xor(q2, off, 64);
          t  += __shfl_xor(t,  off, 64);
        }
        if (cl == 0) {
          const float mu2 = s2 * (1.0f / 128.0f);
          const float var2 = fmaxf(q2 * (1.0f / 128.0f) - mu2 * mu2, 0.0f);
          const float rs2 = rsqrtf(var2 + 1e-5f);
          logits[g0 + mt * 16 + me] = rs2 * (t - mu2 * sgw3) + cb;
        }
      }
    }
  }
}

// ---------------- gumbel argmax, stage 1: per-(bs,chunk) best ----------------
__global__ __launch_bounds__(256) void gumbel_kernel(
    const float* __restrict__ logits, float* __restrict__ bestval,
    int* __restrict__ bestidx) {
  const int bs = blockIdx.x / CHUNKS;     // b*5 + s
  const int chunk = blockIdx.x % CHUNKS;
  const int b = bs / NSAMP;
  const float* lg = logits + b * EDGES;
  float best = -1e30f; int bi = 0x7fffffff;
  for (int e = chunk * 256 + threadIdx.x; e < EDGES; e += CHUNKS * 256) {
    uint32_t n = (uint32_t)(bs * EDGES + e);
    float val = lg[e] + gumbel_valf(n);
    if (val > best) { best = val; bi = e; }
  }
  __shared__ float sv[256];
  __shared__ int si[256];
  sv[threadIdx.x] = best; si[threadIdx.x] = bi;
  __syncthreads();
  for (int off = 128; off; off >>= 1) {
    if (threadIdx.x < off) {
      float ov = sv[threadIdx.x + off]; int oi = si[threadIdx.x + off];
      if (ov > sv[threadIdx.x] ||
          (ov == sv[threadIdx.x] && oi < si[threadIdx.x])) {
        sv[threadIdx.x] = ov; si[threadIdx.x] = oi;
      }
    }
    __syncthreads();
  }
  if (threadIdx.x == 0) { bestval[blockIdx.x] = sv[0]; bestidx[blockIdx.x] = si[0]; }
}

// ---------------- gumbel argmax, stage 2: winner -> adj ----------------------
__global__ __launch_bounds__(64) void select_kernel(
    const float* __restrict__ bestval, const int* __restrict__ bestidx,
    const int2* __restrict__ map, float* __restrict__ adj) {
  const int bs = blockIdx.x;
  const int lane = threadIdx.x;
  float v = -1e30f; int idx = 0x7fffffff;
  if (lane < CHUNKS) { v = bestval[bs * CHUNKS + lane]; idx = bestidx[bs * CHUNKS + lane]; }
#pragma unroll
  for (int off = 32; off; off >>= 1) {
    float ov = __shfl_xor(v, off, 64);
    int oi = __shfl_xor(idx, off, 64);
    if (ov > v || (ov == v && oi < idx)) { v = ov; idx = oi; }
  }
  if (lane == 0) {
    int b = bs / NSAMP;
    int2 ss = map[idx];
    adj[((b * NNODES) + ss.x) * NNODES + ss.y] = 1.0f;
  }
}

extern "C" void kernel_launch(void* const* d_in, const int* in_sizes, int n_in,
                              void* d_out, int out_size, void* d_ws, size_t ws_size,
                              hipStream_t stream) {
  const float* nodes = (const float*)d_in[0];
  const float* W1  = (const float*)d_in[1];
  const float* b1  = (const float*)d_in[2];
  const float* g1  = (const float*)d_in[3];
  const float* be1 = (const float*)d_in[4];
  const float* W2  = (const float*)d_in[5];
  const float* b2  = (const float*)d_in[6];
  const float* g2  = (const float*)d_in[7];
  const float* be2 = (const float*)d_in[8];
  const float* W3  = (const float*)d_in[9];
  const float* b3  = (const float*)d_in[10];
  float* adj = (float*)d_out;

  char* ws = (char*)d_ws;
  float* P       = (float*)(ws);                       // 1 MB  [2048][128]
  float* Q       = (float*)(ws + (1 << 20));           // 1 MB
  int2*  map     = (int2*) (ws + (2 << 20));           // 783 KB
  float* logits  = (float*)(ws + (3 << 20));           // 1.57 MB
  unsigned short* GFH = (unsigned short*)(ws + (5 << 20));           // 32 KB
  unsigned short* GFL = (unsigned short*)(ws + (5 << 20) + 32768);   // 32 KB
  float* SG      = (float*)(ws + (5 << 20) + 65536);
  float* SB      = (float*)(ws + (5 << 20) + 66048);
  float* GW3     = (float*)(ws + (5 << 20) + 66560);
  float* SC      = (float*)(ws + (5 << 20) + 67072);
  float* bestval = (float*)(ws + (5 << 20) + 131072);  // 800*4
  int*   bestidx = (int*)  (ws + (5 << 20) + 137472);  // 800*4

  hipMemsetAsync(adj, 0, (size_t)out_size * sizeof(float), stream);
  setup_kernel<<<256 + MAP_BLOCKS + 1, 256, 0, stream>>>(
      nodes, W1, b1, W2, g1, be1, b2, g2, be2, W3, b3,
      P, Q, map, GFH, GFL, SG, SB, GW3, SC);
  mlp_kernel<<<MLP_GRID, 256, 0, stream>>>(P, Q, map, GFH, GFL,
                                           SG, SB, GW3, SC, logits);
  gumbel_kernel<<<20 * CHUNKS, 256, 0, stream>>>(logits, bestval, bestidx);
  select_kernel<<<20, 64, 0, stream>>>(bestval, bestidx, map, adj);
}